// Round 6
// baseline (513.930 us; speedup 1.0000x reference)
//
#include <hip/hip_runtime.h>
#include <hip/hip_bf16.h>

#define B_   128
#define S_   512
#define H_   128
#define G_   512   // 4*H
#define EMB_ 128
#define NL_  9

typedef __attribute__((ext_vector_type(8))) short bf16x8;
typedef __attribute__((ext_vector_type(4))) short bf16x4;
typedef __attribute__((ext_vector_type(4))) float f32x4;
typedef unsigned short ushort_t;

// LDS-only barrier: vmem ops stay in flight across it.
__device__ __forceinline__ void wg_bar() {
    asm volatile("s_waitcnt lgkmcnt(0)\n\ts_barrier" ::: "memory");
}

__device__ __forceinline__ float bfbits2f(short s) {
    unsigned int u = ((unsigned int)(unsigned short)s) << 16;
    return __builtin_bit_cast(float, u);
}
__device__ __forceinline__ short f2bf(float f) {
    unsigned int u = __builtin_bit_cast(unsigned int, f);
    u += 0x7FFFu + ((u >> 16) & 1u);
    return (short)(u >> 16);
}
__device__ __forceinline__ unsigned int pack2(float lo, float hi) {
    return (unsigned int)(unsigned short)f2bf(lo) | ((unsigned int)(unsigned short)f2bf(hi) << 16);
}
// raw transcendentals: avoid libm guard expansions.
__device__ __forceinline__ float exp2_(float x) {
    float r; asm("v_exp_f32 %0, %1" : "=v"(r) : "v"(x)); return r;
}
__device__ __forceinline__ float log2_(float x) {
    float r; asm("v_log_f32 %0, %1" : "=v"(r) : "v"(x)); return r;
}
__device__ __forceinline__ float max3_(float a, float b, float c) {
    float r; asm("v_max3_f32 %0, %1, %2, %3" : "=v"(r) : "v"(a), "v"(b), "v"(c)); return r;
}
__device__ __forceinline__ float tanh_(float x) {
    return 1.f - 2.f * __builtin_amdgcn_rcpf(1.f + exp2_(2.8853900817779268f * x));
}
__device__ __forceinline__ bf16x8 cvt8(float4 a, float4 b) {
    bf16x8 r;
    r[0] = f2bf(a.x); r[1] = f2bf(a.y); r[2] = f2bf(a.z); r[3] = f2bf(a.w);
    r[4] = f2bf(b.x); r[5] = f2bf(b.y); r[6] = f2bf(b.z); r[7] = f2bf(b.w);
    return r;
}

// ---------------------------------------------------------------------------
// Fused BiLSTM: the xw = emb@W_ih^T + bias pre-pass is computed IN-KERNEL,
// per 16-step block, as a mini-GEMM (32 MFMAs/wave/block = 2/step amortized):
//   - W_ih fragments kept resident in VGPRs (same layout as W_hh frags).
//   - A-frags gathered straight from emb: lane(n16,quad) reads
//     emb[tok[n16]][ks*32+quad*8..+8] — exactly the MFMA A-frag layout.
//   - Output packed bf16 (identical f2bf rounding as the old pre-pass) into
//     the same xwL double buffer -> recurrent math is bit-identical to r4.
// Eliminates the xw_gemm kernel and its 134 MB HBM intermediate entirely.
// Schedule within each 16-step block (m<31):
//   s4==0,k==0: issue token+emb loads for block m+1 (8x float4)
//   s4==1,k==0/2: convert to A-frags (f2bf)
//   s4==2,k==0/2: mini-GEMM tile 0 / tile 1 + LDS writes into buf (m&1)^1
// NOTE r5 bug fixed here: xwL buffer stride is 8192 SHORTS (16 slots x 512
// gates), the write used bufsel*16384 -> OOB into hbuf -> NaN. Now *8192.
// ---------------------------------------------------------------------------
#define MINIGEMM(tl, bufsel)                                                       \
    {                                                                              \
      f32x4 x0 = {biasI[tl][0], biasI[tl][0], biasI[tl][0], biasI[tl][0]};         \
      f32x4 x1 = {biasI[tl][1], biasI[tl][1], biasI[tl][1], biasI[tl][1]};         \
      f32x4 x2 = {biasI[tl][2], biasI[tl][2], biasI[tl][2], biasI[tl][2]};         \
      f32x4 x3 = {biasI[tl][3], biasI[tl][3], biasI[tl][3], biasI[tl][3]};         \
      x0 = __builtin_amdgcn_mfma_f32_16x16x32_bf16(afE0, bfragI[tl][0][0], x0, 0, 0, 0); \
      x1 = __builtin_amdgcn_mfma_f32_16x16x32_bf16(afE0, bfragI[tl][1][0], x1, 0, 0, 0); \
      x2 = __builtin_amdgcn_mfma_f32_16x16x32_bf16(afE0, bfragI[tl][2][0], x2, 0, 0, 0); \
      x3 = __builtin_amdgcn_mfma_f32_16x16x32_bf16(afE0, bfragI[tl][3][0], x3, 0, 0, 0); \
      x0 = __builtin_amdgcn_mfma_f32_16x16x32_bf16(afE1, bfragI[tl][0][1], x0, 0, 0, 0); \
      x1 = __builtin_amdgcn_mfma_f32_16x16x32_bf16(afE1, bfragI[tl][1][1], x1, 0, 0, 0); \
      x2 = __builtin_amdgcn_mfma_f32_16x16x32_bf16(afE1, bfragI[tl][2][1], x2, 0, 0, 0); \
      x3 = __builtin_amdgcn_mfma_f32_16x16x32_bf16(afE1, bfragI[tl][3][1], x3, 0, 0, 0); \
      x0 = __builtin_amdgcn_mfma_f32_16x16x32_bf16(afE2, bfragI[tl][0][2], x0, 0, 0, 0); \
      x1 = __builtin_amdgcn_mfma_f32_16x16x32_bf16(afE2, bfragI[tl][1][2], x1, 0, 0, 0); \
      x2 = __builtin_amdgcn_mfma_f32_16x16x32_bf16(afE2, bfragI[tl][2][2], x2, 0, 0, 0); \
      x3 = __builtin_amdgcn_mfma_f32_16x16x32_bf16(afE2, bfragI[tl][3][2], x3, 0, 0, 0); \
      x0 = __builtin_amdgcn_mfma_f32_16x16x32_bf16(afE3, bfragI[tl][0][3], x0, 0, 0, 0); \
      x1 = __builtin_amdgcn_mfma_f32_16x16x32_bf16(afE3, bfragI[tl][1][3], x1, 0, 0, 0); \
      x2 = __builtin_amdgcn_mfma_f32_16x16x32_bf16(afE3, bfragI[tl][2][3], x2, 0, 0, 0); \
      x3 = __builtin_amdgcn_mfma_f32_16x16x32_bf16(afE3, bfragI[tl][3][3], x3, 0, 0, 0); \
      short* dstp = xwSW + (bufsel) * 8192 + (wv * 32 + (tl) * 16 + n16) * 4;      \
      _Pragma("unroll")                                                            \
      for (int r = 0; r < 4; r++) {                                                \
        uint2 wq; wq.x = pack2(x0[r], x1[r]); wq.y = pack2(x2[r], x3[r]);          \
        *(uint2*)(dstp + (quad * 4 + r) * 512) = wq;                               \
      }                                                                            \
    }

#define STEPK(k)                                                                   \
  {                                                                                \
    if ((k) == 0 && s4 == 0 && m < 31) {                                           \
      int t0s = dir ? (S_ - 32 - m16) : (m16 + 16);                                \
      int tok = seq[b * S_ + t0s + n16];                                           \
      const float* ep = emb + (size_t)tok * EMB_ + quad * 8;                       \
      e0 = *(const float4*)(ep);        e1 = *(const float4*)(ep + 4);             \
      e2 = *(const float4*)(ep + 32);   e3 = *(const float4*)(ep + 36);            \
      e4 = *(const float4*)(ep + 64);   e5 = *(const float4*)(ep + 68);            \
      e6 = *(const float4*)(ep + 96);   e7 = *(const float4*)(ep + 100);           \
    }                                                                              \
    bf16x8 af0 = hbuf[(k) & 1][0 * 4 + quad];                                      \
    bf16x8 af1 = hbuf[(k) & 1][1 * 4 + quad];                                      \
    bf16x8 af2 = hbuf[(k) & 1][2 * 4 + quad];                                      \
    bf16x8 af3 = hbuf[(k) & 1][3 * 4 + quad];                                      \
    const int KE = s4x4 + (k);                                                     \
    const int slot = dir ? (15 - KE) : KE;                                         \
    bf16x4 xvg = *(const bf16x4*)(xwS + (m & 1) * 8192 + slot * 512 + uu * 4);     \
    if ((k) == 0 && s4 == 1 && m < 31) { afE0 = cvt8(e0, e1); afE1 = cvt8(e2, e3); } \
    if ((k) == 2 && s4 == 1 && m < 31) { afE2 = cvt8(e4, e5); afE3 = cvt8(e6, e7); } \
    if ((k) == 0 && s4 == 2 && m < 31) MINIGEMM(0, ((m & 1) ^ 1))                  \
    if ((k) == 2 && s4 == 2 && m < 31) MINIGEMM(1, ((m & 1) ^ 1))                  \
    if ((k) == 1 && s4 == 0 && m >= 1 && wv == 3 && lane < 36) {                   \
      int a0 = dir ? (S_ - m16) : (m16 - 16);                                      \
      float4 fv = *(const float4*)(emL + (a0 & 31) * 9 + lane * 4);                \
      *(float4*)(emdir + (size_t)b * (S_ * NL_) + a0 * NL_ + lane * 4) = fv;       \
    }                                                                              \
    f32x4 aA0 = __builtin_amdgcn_mfma_f32_16x16x32_bf16(af0, bfrag[0][0][0], ZACC, 0, 0, 0); \
    f32x4 aA1 = __builtin_amdgcn_mfma_f32_16x16x32_bf16(af0, bfrag[0][1][0], ZACC, 0, 0, 0); \
    f32x4 aA2 = __builtin_amdgcn_mfma_f32_16x16x32_bf16(af0, bfrag[0][2][0], ZACC, 0, 0, 0); \
    f32x4 aA3 = __builtin_amdgcn_mfma_f32_16x16x32_bf16(af0, bfrag[0][3][0], ZACC, 0, 0, 0); \
    f32x4 aB0 = __builtin_amdgcn_mfma_f32_16x16x32_bf16(af0, bfrag[1][0][0], ZACC, 0, 0, 0); \
    f32x4 aB1 = __builtin_amdgcn_mfma_f32_16x16x32_bf16(af0, bfrag[1][1][0], ZACC, 0, 0, 0); \
    f32x4 aB2 = __builtin_amdgcn_mfma_f32_16x16x32_bf16(af0, bfrag[1][2][0], ZACC, 0, 0, 0); \
    f32x4 aB3 = __builtin_amdgcn_mfma_f32_16x16x32_bf16(af0, bfrag[1][3][0], ZACC, 0, 0, 0); \
    aA0 = __builtin_amdgcn_mfma_f32_16x16x32_bf16(af1, bfrag[0][0][1], aA0, 0, 0, 0); \
    aA1 = __builtin_amdgcn_mfma_f32_16x16x32_bf16(af1, bfrag[0][1][1], aA1, 0, 0, 0); \
    aA2 = __builtin_amdgcn_mfma_f32_16x16x32_bf16(af1, bfrag[0][2][1], aA2, 0, 0, 0); \
    aA3 = __builtin_amdgcn_mfma_f32_16x16x32_bf16(af1, bfrag[0][3][1], aA3, 0, 0, 0); \
    aB0 = __builtin_amdgcn_mfma_f32_16x16x32_bf16(af1, bfrag[1][0][1], aB0, 0, 0, 0); \
    aB1 = __builtin_amdgcn_mfma_f32_16x16x32_bf16(af1, bfrag[1][1][1], aB1, 0, 0, 0); \
    aB2 = __builtin_amdgcn_mfma_f32_16x16x32_bf16(af1, bfrag[1][2][1], aB2, 0, 0, 0); \
    aB3 = __builtin_amdgcn_mfma_f32_16x16x32_bf16(af1, bfrag[1][3][1], aB3, 0, 0, 0); \
    aA0 = __builtin_amdgcn_mfma_f32_16x16x32_bf16(af2, bfrag[0][0][2], aA0, 0, 0, 0); \
    aA1 = __builtin_amdgcn_mfma_f32_16x16x32_bf16(af2, bfrag[0][1][2], aA1, 0, 0, 0); \
    aA2 = __builtin_amdgcn_mfma_f32_16x16x32_bf16(af2, bfrag[0][2][2], aA2, 0, 0, 0); \
    aA3 = __builtin_amdgcn_mfma_f32_16x16x32_bf16(af2, bfrag[0][3][2], aA3, 0, 0, 0); \
    aB0 = __builtin_amdgcn_mfma_f32_16x16x32_bf16(af2, bfrag[1][0][2], aB0, 0, 0, 0); \
    aB1 = __builtin_amdgcn_mfma_f32_16x16x32_bf16(af2, bfrag[1][1][2], aB1, 0, 0, 0); \
    aB2 = __builtin_amdgcn_mfma_f32_16x16x32_bf16(af2, bfrag[1][2][2], aB2, 0, 0, 0); \
    aB3 = __builtin_amdgcn_mfma_f32_16x16x32_bf16(af2, bfrag[1][3][2], aB3, 0, 0, 0); \
    aA0 = __builtin_amdgcn_mfma_f32_16x16x32_bf16(af3, bfrag[0][0][3], aA0, 0, 0, 0); \
    aA1 = __builtin_amdgcn_mfma_f32_16x16x32_bf16(af3, bfrag[0][1][3], aA1, 0, 0, 0); \
    aA2 = __builtin_amdgcn_mfma_f32_16x16x32_bf16(af3, bfrag[0][2][3], aA2, 0, 0, 0); \
    aA3 = __builtin_amdgcn_mfma_f32_16x16x32_bf16(af3, bfrag[0][3][3], aA3, 0, 0, 0); \
    aB0 = __builtin_amdgcn_mfma_f32_16x16x32_bf16(af3, bfrag[1][0][3], aB0, 0, 0, 0); \
    aB1 = __builtin_amdgcn_mfma_f32_16x16x32_bf16(af3, bfrag[1][1][3], aB1, 0, 0, 0); \
    aB2 = __builtin_amdgcn_mfma_f32_16x16x32_bf16(af3, bfrag[1][2][3], aB2, 0, 0, 0); \
    aB3 = __builtin_amdgcn_mfma_f32_16x16x32_bf16(af3, bfrag[1][3][3], aB3, 0, 0, 0); \
    {                                                                              \
      float gi = ((quad & 2) ? aB0[0] : aA0[0]) + bfbits2f(xvg[0]);                \
      float gf = ((quad & 2) ? aB1[0] : aA1[0]) + bfbits2f(xvg[1]);                \
      float gg = ((quad & 2) ? aB2[0] : aA2[0]) + bfbits2f(xvg[2]);                \
      float go = ((quad & 2) ? aB3[0] : aA3[0]) + bfbits2f(xvg[3]);                \
      float Af = exp2_(-1.4426950408889634f * gf);                                 \
      float Bi = exp2_(-1.4426950408889634f * gi);                                 \
      float Cg = exp2_(2.8853900817779268f * gg);                                  \
      float Fo = exp2_(-1.4426950408889634f * go);                                 \
      float oA = 1.f + Af, oB = 1.f + Bi, oC = 1.f + Cg;                           \
      float P = oB * oC;                                                           \
      float numer = cst * P + oA * (Cg - 1.f);                                     \
      cst = numer * __builtin_amdgcn_rcpf(oA * P);                                 \
      float hv = tanh_(cst) * __builtin_amdgcn_rcpf(1.f + Fo);                     \
      if (!(quad & 1)) *(((k) & 1) ? hw0 : hw1) = f2bf(hv);                        \
    }                                                                              \
    if (wv == 0) {                                                                 \
      f32x4 accE = __builtin_amdgcn_mfma_f32_16x16x32_bf16(af0, bfragE[0], ZACC, 0, 0, 0); \
      accE = __builtin_amdgcn_mfma_f32_16x16x32_bf16(af1, bfragE[1], accE, 0, 0, 0); \
      accE = __builtin_amdgcn_mfma_f32_16x16x32_bf16(af2, bfragE[2], accE, 0, 0, 0); \
      accE = __builtin_amdgcn_mfma_f32_16x16x32_bf16(af3, bfragE[3], accE, 0, 0, 0); \
      if (quad == 0 && n16 < NL_ && (m16 + KE) >= 1) {                             \
        int tprev = dir ? (S_ - (m16 + KE)) : (m16 + KE - 1);                      \
        emL[(tprev & 31) * 9 + n16] = accE[0];                                     \
      }                                                                            \
    }                                                                              \
    wg_bar();                                                                      \
  }

__global__ __launch_bounds__(256, 1)
void lstm_kernel(const int* __restrict__ seq, const float* __restrict__ emb,
                 const float* __restrict__ w_ih_f, const float* __restrict__ b_ih_f,
                 const float* __restrict__ b_hh_f,
                 const float* __restrict__ w_ih_b, const float* __restrict__ b_ih_b,
                 const float* __restrict__ b_hh_b,
                 const float* __restrict__ w_hh_f, const float* __restrict__ w_hh_b,
                 const float* __restrict__ w_out,
                 float* __restrict__ em_f, float* __restrict__ em_b)
{
    __shared__ bf16x8 xwL[2 * 1024];           // 32 KB: [buf][t*512 + u*4 + nt] ushorts
    __shared__ bf16x8 hbuf[2][16];             // 512 B, double-buffered h (128 bf16/buf)
    __shared__ __align__(16) float emL[32 * NL_];  // 1152 B: [slot][label]

    const int tid  = threadIdx.x;
    const int wv   = tid >> 6;
    const int lane = tid & 63;
    const int n16  = tid & 15;
    const int quad = (tid & 63) >> 4;
    const int dir  = blockIdx.x >> 7;
    const int b    = blockIdx.x & 127;

    const int uu = wv * 32 + ((quad >> 1) << 4) + n16;   // unit owned by this lane

    // per-lane h-write pointers (buf0/buf1); writers are quads 0 and 2
    short* hw0 = ((short*)hbuf) + uu;
    short* hw1 = ((short*)hbuf) + 128 + uu;
    const short* xwS = (const short*)xwL;
    short* xwSW = (short*)xwL;

    const f32x4 ZACC = {0.f, 0.f, 0.f, 0.f};

    const float* whh = dir ? w_hh_b : w_hh_f;
    const float* wih = dir ? w_ih_b : w_ih_f;
    const float* bih = dir ? b_ih_b : b_ih_f;
    const float* bhh = dir ? b_hh_b : b_hh_f;
    float* emdir = dir ? em_b : em_f;

    // W_hh fragments: bfrag[tile][gate][ks]; gate col = nt*128 + wv*32 + tl*16 + n16
    bf16x8 bfrag[2][4][4];
#pragma unroll
    for (int tl = 0; tl < 2; tl++) {
#pragma unroll
        for (int nt = 0; nt < 4; nt++) {
            int col = nt * 128 + wv * 32 + tl * 16 + n16;
#pragma unroll
            for (int ks = 0; ks < 4; ks++) {
                const float* p = whh + col * H_ + ks * 32 + quad * 8;
                bf16x8 fr;
#pragma unroll
                for (int j = 0; j < 8; j++) fr[j] = f2bf(p[j]);
                bfrag[tl][nt][ks] = fr;
            }
        }
    }
    // W_ih fragments (resident) + fused bias, same column mapping
    bf16x8 bfragI[2][4][4];
    float  biasI[2][4];
#pragma unroll
    for (int tl = 0; tl < 2; tl++) {
#pragma unroll
        for (int nt = 0; nt < 4; nt++) {
            int col = nt * 128 + wv * 32 + tl * 16 + n16;
            biasI[tl][nt] = bih[col] + bhh[col];
#pragma unroll
            for (int ks = 0; ks < 4; ks++) {
                const float* p = wih + col * EMB_ + ks * 32 + quad * 8;
                bf16x8 fr;
#pragma unroll
                for (int j = 0; j < 8; j++) fr[j] = f2bf(p[j]);
                bfragI[tl][nt][ks] = fr;
            }
        }
    }
    bf16x8 bfragE[4];
#pragma unroll
    for (int ks = 0; ks < 4; ks++) {
        bf16x8 fr = {0, 0, 0, 0, 0, 0, 0, 0};
        if (n16 < NL_) {
            const float* p = w_out + n16 * 256 + dir * 128 + ks * 32 + quad * 8;
#pragma unroll
            for (int j = 0; j < 8; j++) fr[j] = f2bf(p[j]);
        }
        bfragE[ks] = fr;
    }

    if (tid < 64) ((int*)hbuf)[tid] = 0;   // zero h buffer 0 (256 B)

    float4 e0, e1, e2, e3, e4, e5, e6, e7;
    bf16x8 afE0, afE1, afE2, afE3;

    // prolog: compute block 0's xw tile into buf 0
    {
        int t0s = dir ? (S_ - 16) : 0;
        int tok = seq[b * S_ + t0s + n16];
        const float* ep = emb + (size_t)tok * EMB_ + quad * 8;
        e0 = *(const float4*)(ep);        e1 = *(const float4*)(ep + 4);
        e2 = *(const float4*)(ep + 32);   e3 = *(const float4*)(ep + 36);
        e4 = *(const float4*)(ep + 64);   e5 = *(const float4*)(ep + 68);
        e6 = *(const float4*)(ep + 96);   e7 = *(const float4*)(ep + 100);
        afE0 = cvt8(e0, e1); afE1 = cvt8(e2, e3);
        afE2 = cvt8(e4, e5); afE3 = cvt8(e6, e7);
        MINIGEMM(0, 0)
        MINIGEMM(1, 0)
    }

    float cst = 0.f;
    wg_bar();

#pragma unroll 1
    for (int m = 0; m < 32; m++) {
        const int m16 = m << 4;
#pragma unroll 1
        for (int s4 = 0; s4 < 4; s4++) {
            const int s4x4 = s4 << 2;
            STEPK(0) STEPK(1) STEPK(2) STEPK(3)
        }
    }

    // final emission (h after step 512, in buf0), then tail flush
    if (wv == 0) {
        bf16x8 af0 = hbuf[0][0 * 4 + quad];
        bf16x8 af1 = hbuf[0][1 * 4 + quad];
        bf16x8 af2 = hbuf[0][2 * 4 + quad];
        bf16x8 af3 = hbuf[0][3 * 4 + quad];
        f32x4 accE = __builtin_amdgcn_mfma_f32_16x16x32_bf16(af0, bfragE[0], ZACC, 0, 0, 0);
        accE = __builtin_amdgcn_mfma_f32_16x16x32_bf16(af1, bfragE[1], accE, 0, 0, 0);
        accE = __builtin_amdgcn_mfma_f32_16x16x32_bf16(af2, bfragE[2], accE, 0, 0, 0);
        accE = __builtin_amdgcn_mfma_f32_16x16x32_bf16(af3, bfragE[3], accE, 0, 0, 0);
        if (quad == 0 && n16 < NL_) {
            int tprev = dir ? 0 : (S_ - 1);
            emL[(tprev & 31) * 9 + n16] = accE[0];
        }
    }
    wg_bar();
    if (wv == 3 && lane < 36) {
        int a0 = dir ? 0 : (S_ - 16);
        float4 fv = *(const float4*)(emL + (a0 & 31) * 9 + lane * 4);
        *(float4*)(emdir + (size_t)b * (S_ * NL_) + a0 * NL_ + lane * 4) = fv;
    }
}

// ---------------------------------------------------------------------------
// CRF with chunked parallel scan. Inner loop upgraded: v_max3 tree for the
// 9-way max, raw v_exp/v_log (same trick verified in lstm).
// ---------------------------------------------------------------------------
__global__ __launch_bounds__(640, 1)
void crf_kernel(const int* __restrict__ seq, const int* __restrict__ lab,
                const float* __restrict__ em_f, const float* __restrict__ em_b,
                const float* __restrict__ b_out,
                const float* __restrict__ start_t, const float* __restrict__ end_t,
                const float* __restrict__ trans, float* __restrict__ partial)
{
    __shared__ float emS[S_ * NL_];
    __shared__ float transS[NL_ * NL_];
    __shared__ float stS[NL_], enS[NL_];
    __shared__ unsigned char maskS[S_];
    __shared__ float MS[7 * 81];
    __shared__ float vS[NL_];
    __shared__ float redw[10];
    __shared__ int   redl[10];

    const int b = blockIdx.x, tid = threadIdx.x;
    const size_t base = (size_t)b * S_ * NL_;
    const float L2E = 1.4426950408889634f, LN2 = 0.6931471805599453f;

    for (int q = tid; q < S_ * NL_; q += 640)
        emS[q] = em_f[base + q] + em_b[base + q] + b_out[q % NL_];
    if (tid < NL_ * NL_) transS[tid] = trans[tid];
    if (tid < NL_) { stS[tid] = start_t[tid]; enS[tid] = end_t[tid]; }
    if (tid < S_) maskS[tid] = (seq[b * S_ + tid] != 0);
    __syncthreads();

    float np = 0.f; int myc = 0;
    if (tid < S_) {
        myc = maskS[tid];
        if (tid >= 1 && maskS[tid]) {
            int lp = lab[b * S_ + tid - 1], lc = lab[b * S_ + tid];
            np = transS[lp * NL_ + lc] + emS[tid * NL_ + lc];
        }
    }
#pragma unroll
    for (int off = 32; off; off >>= 1) {
        np  += __shfl_down(np, off, 64);
        myc += __shfl_down(myc, off, 64);
    }
    if ((tid & 63) == 0) { redw[tid >> 6] = np; redl[tid >> 6] = myc; }

    const int w = tid >> 6, l = tid & 63;
    const int lg = l / 9;
    const int g  = w * 7 + lg;
    const bool sact = (lg < 7) && (g < 64);
    const int jj = sact ? (l - lg * 9) : 0;
    const int gb = sact ? lg * 9 : 0;
    float Tc[NL_];
#pragma unroll
    for (int i = 0; i < NL_; i++) Tc[i] = transS[i * NL_ + jj];
    float sc; int tbeg, tend, cN = 0, iN = 0;
    if (sact && g == 0) {
        sc = stS[jj] + emS[jj];
        tbeg = 1; tend = 64;
    } else if (sact) {
        cN = 1 + (g - 1) / 9; iN = (g - 1) % 9;
        sc = (jj == iN) ? 0.f : -1e30f;
        tbeg = cN * 64; tend = tbeg + 64;
    } else {
        sc = -1e30f; tbeg = 448; tend = 512;
    }
    for (int t = tbeg; t < tend; t++) {
        float emv = emS[t * NL_ + jj];
        float a[NL_];
#pragma unroll
        for (int i = 0; i < NL_; i++) a[i] = __shfl(sc, gb + i, 64) + Tc[i];
        float m = max3_(max3_(a[0], a[1], a[2]), max3_(a[3], a[4], a[5]),
                        max3_(a[6], a[7], a[8]));
        float e[NL_];
#pragma unroll
        for (int i = 0; i < NL_; i++) e[i] = exp2_((a[i] - m) * L2E);
        float sum = ((e[0] + e[1]) + (e[2] + e[3])) + ((e[4] + e[5]) + (e[6] + e[7])) + e[8];
        float nxt = emv + m + LN2 * log2_(sum);
        sc = maskS[t] ? nxt : sc;
    }
    if (sact) {
        if (g == 0) vS[jj] = sc;
        else MS[(cN - 1) * 81 + iN * NL_ + jj] = sc;
    }
    __syncthreads();

    if (tid < 64) {
        const int j = (tid < NL_) ? tid : (NL_ - 1);
        float v = vS[j];
        for (int c = 1; c < 8; c++) {
            float a[NL_];
#pragma unroll
            for (int i = 0; i < NL_; i++)
                a[i] = __shfl(v, i, 64) + MS[(c - 1) * 81 + i * NL_ + j];
            float m = max3_(max3_(a[0], a[1], a[2]), max3_(a[3], a[4], a[5]),
                            max3_(a[6], a[7], a[8]));
            float e[NL_];
#pragma unroll
            for (int i = 0; i < NL_; i++) e[i] = exp2_((a[i] - m) * L2E);
            float sum = ((e[0] + e[1]) + (e[2] + e[3])) + ((e[4] + e[5]) + (e[6] + e[7])) + e[8];
            v = m + LN2 * log2_(sum);
        }
        v += enS[j];
        float mm = -1e30f, av[NL_];
#pragma unroll
        for (int i = 0; i < NL_; i++) { float vi = __shfl(v, i, 64); av[i] = vi; mm = fmaxf(mm, vi); }
        float ss = 0.f;
#pragma unroll
        for (int i = 0; i < NL_; i++) ss += exp2_((av[i] - mm) * L2E);
        if (tid == 0) {
            float num = 0.f; int len = 0;
#pragma unroll
            for (int ww = 0; ww < 10; ww++) { num += redw[ww]; len += redl[ww]; }
            int l0 = lab[b * S_];
            int ll = lab[b * S_ + len - 1];
            num += stS[l0] + emS[l0] + enS[ll];
            partial[b] = (mm + LN2 * log2_(ss)) - num;
        }
    }
}

__global__ __launch_bounds__(128)
void reduce_kernel(const float* __restrict__ partial, float* __restrict__ out)
{
    __shared__ float s[128];
    int tid = threadIdx.x;
    s[tid] = partial[tid];
    __syncthreads();
    for (int off = 64; off; off >>= 1) {
        if (tid < off) s[tid] += s[tid + off];
        __syncthreads();
    }
    if (tid == 0) out[0] = s[0];
}

extern "C" void kernel_launch(void* const* d_in, const int* in_sizes, int n_in,
                              void* d_out, int out_size, void* d_ws, size_t ws_size,
                              hipStream_t stream)
{
    const int* seq = (const int*)d_in[0];
    const int* lab = (const int*)d_in[1];
    const float* emb    = (const float*)d_in[2];
    const float* w_ih_f = (const float*)d_in[3];
    const float* w_hh_f = (const float*)d_in[4];
    const float* b_ih_f = (const float*)d_in[5];
    const float* b_hh_f = (const float*)d_in[6];
    const float* w_ih_b = (const float*)d_in[7];
    const float* w_hh_b = (const float*)d_in[8];
    const float* b_ih_b = (const float*)d_in[9];
    const float* b_hh_b = (const float*)d_in[10];
    const float* w_out  = (const float*)d_in[11];
    const float* b_out  = (const float*)d_in[12];
    const float* start_t = (const float*)d_in[13];
    const float* end_t   = (const float*)d_in[14];
    const float* trans   = (const float*)d_in[15];

    char* ws = (char*)d_ws;
    const size_t em_bytes = (size_t)B_ * S_ * NL_ * sizeof(float);
    float* em_f    = (float*)ws;
    float* em_b    = (float*)(ws + em_bytes);
    float* partial = (float*)(ws + 2 * em_bytes);

    lstm_kernel<<<dim3(256), dim3(256), 0, stream>>>(seq, emb,
        w_ih_f, b_ih_f, b_hh_f, w_ih_b, b_ih_b, b_hh_b,
        w_hh_f, w_hh_b, w_out, em_f, em_b);
    crf_kernel<<<dim3(B_), dim3(640), 0, stream>>>(seq, lab, em_f, em_b, b_out,
        start_t, end_t, trans, partial);
    reduce_kernel<<<dim3(1), dim3(128), 0, stream>>>(partial, (float*)d_out);
}

// Round 7
// 492.060 us; speedup vs baseline: 1.0444x; 1.0444x over previous
//
#include <hip/hip_runtime.h>
#include <hip/hip_bf16.h>

#define B_   128
#define S_   512
#define H_   128
#define G_   512   // 4*H
#define EMB_ 128
#define NL_  9

typedef __attribute__((ext_vector_type(8))) short bf16x8;
typedef __attribute__((ext_vector_type(4))) short bf16x4;
typedef __attribute__((ext_vector_type(4))) float f32x4;
typedef unsigned short ushort_t;

// LDS-only barrier: vmem ops stay in flight across it.
__device__ __forceinline__ void wg_bar() {
    asm volatile("s_waitcnt lgkmcnt(0)\n\ts_barrier" ::: "memory");
}

__device__ __forceinline__ float bfbits2f(short s) {
    unsigned int u = ((unsigned int)(unsigned short)s) << 16;
    return __builtin_bit_cast(float, u);
}
__device__ __forceinline__ short f2bf(float f) {
    unsigned int u = __builtin_bit_cast(unsigned int, f);
    u += 0x7FFFu + ((u >> 16) & 1u);
    return (short)(u >> 16);
}
__device__ __forceinline__ unsigned int pack2(float lo, float hi) {
    return (unsigned int)(unsigned short)f2bf(lo) | ((unsigned int)(unsigned short)f2bf(hi) << 16);
}
// raw transcendentals: avoid libm guard expansions.
__device__ __forceinline__ float exp2_(float x) {
    float r; asm("v_exp_f32 %0, %1" : "=v"(r) : "v"(x)); return r;
}
__device__ __forceinline__ float log2_(float x) {
    float r; asm("v_log_f32 %0, %1" : "=v"(r) : "v"(x)); return r;
}
__device__ __forceinline__ float max3_(float a, float b, float c) {
    float r; asm("v_max3_f32 %0, %1, %2, %3" : "=v"(r) : "v"(a), "v"(b), "v"(c)); return r;
}
__device__ __forceinline__ float tanh_(float x) {
    return 1.f - 2.f * __builtin_amdgcn_rcpf(1.f + exp2_(2.8853900817779268f * x));
}

// ---------------------------------------------------------------------------
// prep_kernel (one dispatch, three jobs by blockIdx):
//   [0,6250)       : emb -> bf16 (embB, 25.6 MB). Same f2bf rounding as before.
//   [6250,6314)    : W_ih -> bf16 fragments in lane order (wihPack, 256 KB):
//                    f = ((((dir*4+wv)*2+tl)*4+ks)*4+nt)*64+lane, 16B each.
//   [6314,6318)    : fused bias b_ih+b_hh (biasPack, 4 KB):
//                    idx = (((dir*4+wv)*2+tl)*16+n16)*4+nt.
// ---------------------------------------------------------------------------
#define NB_EMB 6250
#define NB_WIH 64
__global__ __launch_bounds__(256)
void prep_kernel(const float* __restrict__ emb,
                 const float* __restrict__ w_ih_f, const float* __restrict__ w_ih_b,
                 const float* __restrict__ b_ih_f, const float* __restrict__ b_hh_f,
                 const float* __restrict__ b_ih_b, const float* __restrict__ b_hh_b,
                 ushort_t* __restrict__ embB, ushort_t* __restrict__ wihPack,
                 float* __restrict__ biasPack)
{
    const int bid = blockIdx.x, tid = threadIdx.x;
    if (bid < NB_EMB) {
        int base = (bid * 256 + tid) * 8;   // 6250*256*8 == 100000*128 exactly
        float4 a = *(const float4*)(emb + base);
        float4 c = *(const float4*)(emb + base + 4);
        bf16x8 r;
        r[0] = f2bf(a.x); r[1] = f2bf(a.y); r[2] = f2bf(a.z); r[3] = f2bf(a.w);
        r[4] = f2bf(c.x); r[5] = f2bf(c.y); r[6] = f2bf(c.z); r[7] = f2bf(c.w);
        *(bf16x8*)(embB + base) = r;
    } else if (bid < NB_EMB + NB_WIH) {
        int f = (bid - NB_EMB) * 256 + tid;       // 0..16383
        int lane = f & 63;
        int nt = (f >> 6) & 3;
        int ks = (f >> 8) & 3;
        int tl = (f >> 10) & 1;
        int wv = (f >> 11) & 3;
        int dirq = (f >> 13) & 1;
        int n16 = lane & 15, quad = lane >> 4;
        const float* w = dirq ? w_ih_b : w_ih_f;
        int col = nt * 128 + wv * 32 + tl * 16 + n16;
        const float* p = w + col * EMB_ + ks * 32 + quad * 8;
        bf16x8 r;
#pragma unroll
        for (int j = 0; j < 8; j++) r[j] = f2bf(p[j]);
        *(bf16x8*)(wihPack + f * 8) = r;
    } else {
        int idx = (bid - NB_EMB - NB_WIH) * 256 + tid;
        if (idx < 1024) {
            int nt = idx & 3;
            int n16 = (idx >> 2) & 15;
            int tl = (idx >> 6) & 1;
            int wv = (idx >> 7) & 3;
            int dirq = (idx >> 9) & 1;
            const float* bi = dirq ? b_ih_b : b_ih_f;
            const float* bh = dirq ? b_hh_b : b_hh_f;
            int col = nt * 128 + wv * 32 + tl * 16 + n16;
            biasPack[idx] = bi[col] + bh[col];
        }
    }
}

// ---------------------------------------------------------------------------
// Fused BiLSTM, STREAMED mini-GEMM (fixes r6's scratch spill):
//   - W_ih fragments NOT resident: streamed from L2-resident wihPack,
//     4 x 16B loads + 4 MFMAs per step across 8 steps (s4 in {2,3}).
//   - emb gathered as pre-converted bf16 (embB) directly into A-frags.
//   - x-accumulators: 16 VGPRs live per tile phase; write at k==3.
//   - Resident regs ~206, peak ~270 -> no scratch spill (vs ~420 in r6).
// Numerics bit-identical to r6 (same f2bf roundings, same MFMA order).
// ---------------------------------------------------------------------------
#define AFE_(k) afE##k

#define STEPK(k)                                                                   \
  {                                                                                \
    if ((k) == 0 && s4 == 0 && m < 31) {                                           \
      int t0s = dir ? (S_ - 32 - m16) : (m16 + 16);                                \
      int tok = seq[b * S_ + t0s + n16];                                           \
      const ushort_t* ep = embB + (size_t)tok * EMB_ + quad * 8;                   \
      afE0 = *(const bf16x8*)(ep);                                                 \
      afE1 = *(const bf16x8*)(ep + 32);                                            \
      afE2 = *(const bf16x8*)(ep + 64);                                            \
      afE3 = *(const bf16x8*)(ep + 96);                                            \
    }                                                                              \
    bf16x8 fr0, fr1, fr2, fr3;                                                     \
    int tlr = 0;                                                                   \
    if (s4 >= 2 && m < 31) {                                                       \
      tlr = s4 - 2;                                                                \
      const ushort_t* wp = wvbase + (tlr * 4 + (k)) * 2048;                        \
      fr0 = *(const bf16x8*)(wp);                                                  \
      fr1 = *(const bf16x8*)(wp + 512);                                            \
      fr2 = *(const bf16x8*)(wp + 1024);                                           \
      fr3 = *(const bf16x8*)(wp + 1536);                                           \
      if ((k) == 0) {                                                              \
        float4 bv = tlr ? bb1 : bb0;                                               \
        x0 = (f32x4){bv.x, bv.x, bv.x, bv.x};                                      \
        x1 = (f32x4){bv.y, bv.y, bv.y, bv.y};                                      \
        x2 = (f32x4){bv.z, bv.z, bv.z, bv.z};                                      \
        x3 = (f32x4){bv.w, bv.w, bv.w, bv.w};                                      \
      }                                                                            \
    }                                                                              \
    bf16x8 af0 = hbuf[(k) & 1][0 * 4 + quad];                                      \
    bf16x8 af1 = hbuf[(k) & 1][1 * 4 + quad];                                      \
    bf16x8 af2 = hbuf[(k) & 1][2 * 4 + quad];                                      \
    bf16x8 af3 = hbuf[(k) & 1][3 * 4 + quad];                                      \
    const int KE = s4x4 + (k);                                                     \
    const int slot = dir ? (15 - KE) : KE;                                         \
    bf16x4 xvg = *(const bf16x4*)(xwS + (m & 1) * 8192 + slot * 512 + uu * 4);     \
    if ((k) == 1 && s4 == 0 && m >= 1 && wv == 3 && lane < 36) {                   \
      int a0 = dir ? (S_ - m16) : (m16 - 16);                                      \
      float4 fv = *(const float4*)(emL + (a0 & 31) * 9 + lane * 4);                \
      *(float4*)(emdir + (size_t)b * (S_ * NL_) + a0 * NL_ + lane * 4) = fv;       \
    }                                                                              \
    f32x4 aA0 = __builtin_amdgcn_mfma_f32_16x16x32_bf16(af0, bfrag[0][0][0], ZACC, 0, 0, 0); \
    f32x4 aA1 = __builtin_amdgcn_mfma_f32_16x16x32_bf16(af0, bfrag[0][1][0], ZACC, 0, 0, 0); \
    f32x4 aA2 = __builtin_amdgcn_mfma_f32_16x16x32_bf16(af0, bfrag[0][2][0], ZACC, 0, 0, 0); \
    f32x4 aA3 = __builtin_amdgcn_mfma_f32_16x16x32_bf16(af0, bfrag[0][3][0], ZACC, 0, 0, 0); \
    f32x4 aB0 = __builtin_amdgcn_mfma_f32_16x16x32_bf16(af0, bfrag[1][0][0], ZACC, 0, 0, 0); \
    f32x4 aB1 = __builtin_amdgcn_mfma_f32_16x16x32_bf16(af0, bfrag[1][1][0], ZACC, 0, 0, 0); \
    f32x4 aB2 = __builtin_amdgcn_mfma_f32_16x16x32_bf16(af0, bfrag[1][2][0], ZACC, 0, 0, 0); \
    f32x4 aB3 = __builtin_amdgcn_mfma_f32_16x16x32_bf16(af0, bfrag[1][3][0], ZACC, 0, 0, 0); \
    aA0 = __builtin_amdgcn_mfma_f32_16x16x32_bf16(af1, bfrag[0][0][1], aA0, 0, 0, 0); \
    aA1 = __builtin_amdgcn_mfma_f32_16x16x32_bf16(af1, bfrag[0][1][1], aA1, 0, 0, 0); \
    aA2 = __builtin_amdgcn_mfma_f32_16x16x32_bf16(af1, bfrag[0][2][1], aA2, 0, 0, 0); \
    aA3 = __builtin_amdgcn_mfma_f32_16x16x32_bf16(af1, bfrag[0][3][1], aA3, 0, 0, 0); \
    aB0 = __builtin_amdgcn_mfma_f32_16x16x32_bf16(af1, bfrag[1][0][1], aB0, 0, 0, 0); \
    aB1 = __builtin_amdgcn_mfma_f32_16x16x32_bf16(af1, bfrag[1][1][1], aB1, 0, 0, 0); \
    aB2 = __builtin_amdgcn_mfma_f32_16x16x32_bf16(af1, bfrag[1][2][1], aB2, 0, 0, 0); \
    aB3 = __builtin_amdgcn_mfma_f32_16x16x32_bf16(af1, bfrag[1][3][1], aB3, 0, 0, 0); \
    aA0 = __builtin_amdgcn_mfma_f32_16x16x32_bf16(af2, bfrag[0][0][2], aA0, 0, 0, 0); \
    aA1 = __builtin_amdgcn_mfma_f32_16x16x32_bf16(af2, bfrag[0][1][2], aA1, 0, 0, 0); \
    aA2 = __builtin_amdgcn_mfma_f32_16x16x32_bf16(af2, bfrag[0][2][2], aA2, 0, 0, 0); \
    aA3 = __builtin_amdgcn_mfma_f32_16x16x32_bf16(af2, bfrag[0][3][2], aA3, 0, 0, 0); \
    aB0 = __builtin_amdgcn_mfma_f32_16x16x32_bf16(af2, bfrag[1][0][2], aB0, 0, 0, 0); \
    aB1 = __builtin_amdgcn_mfma_f32_16x16x32_bf16(af2, bfrag[1][1][2], aB1, 0, 0, 0); \
    aB2 = __builtin_amdgcn_mfma_f32_16x16x32_bf16(af2, bfrag[1][2][2], aB2, 0, 0, 0); \
    aB3 = __builtin_amdgcn_mfma_f32_16x16x32_bf16(af2, bfrag[1][3][2], aB3, 0, 0, 0); \
    aA0 = __builtin_amdgcn_mfma_f32_16x16x32_bf16(af3, bfrag[0][0][3], aA0, 0, 0, 0); \
    aA1 = __builtin_amdgcn_mfma_f32_16x16x32_bf16(af3, bfrag[0][1][3], aA1, 0, 0, 0); \
    aA2 = __builtin_amdgcn_mfma_f32_16x16x32_bf16(af3, bfrag[0][2][3], aA2, 0, 0, 0); \
    aA3 = __builtin_amdgcn_mfma_f32_16x16x32_bf16(af3, bfrag[0][3][3], aA3, 0, 0, 0); \
    aB0 = __builtin_amdgcn_mfma_f32_16x16x32_bf16(af3, bfrag[1][0][3], aB0, 0, 0, 0); \
    aB1 = __builtin_amdgcn_mfma_f32_16x16x32_bf16(af3, bfrag[1][1][3], aB1, 0, 0, 0); \
    aB2 = __builtin_amdgcn_mfma_f32_16x16x32_bf16(af3, bfrag[1][2][3], aB2, 0, 0, 0); \
    aB3 = __builtin_amdgcn_mfma_f32_16x16x32_bf16(af3, bfrag[1][3][3], aB3, 0, 0, 0); \
    if (s4 >= 2 && m < 31) {                                                       \
      x0 = __builtin_amdgcn_mfma_f32_16x16x32_bf16(AFE_(k), fr0, x0, 0, 0, 0);     \
      x1 = __builtin_amdgcn_mfma_f32_16x16x32_bf16(AFE_(k), fr1, x1, 0, 0, 0);     \
      x2 = __builtin_amdgcn_mfma_f32_16x16x32_bf16(AFE_(k), fr2, x2, 0, 0, 0);     \
      x3 = __builtin_amdgcn_mfma_f32_16x16x32_bf16(AFE_(k), fr3, x3, 0, 0, 0);     \
      if ((k) == 3) {                                                              \
        short* dstp = xwSW + (((m & 1) ^ 1) * 8192) + (wv * 32 + tlr * 16 + n16) * 4; \
        _Pragma("unroll")                                                          \
        for (int r = 0; r < 4; r++) {                                              \
          uint2 wq; wq.x = pack2(x0[r], x1[r]); wq.y = pack2(x2[r], x3[r]);        \
          *(uint2*)(dstp + (quad * 4 + r) * 512) = wq;                             \
        }                                                                          \
      }                                                                            \
    }                                                                              \
    {                                                                              \
      float gi = ((quad & 2) ? aB0[0] : aA0[0]) + bfbits2f(xvg[0]);                \
      float gf = ((quad & 2) ? aB1[0] : aA1[0]) + bfbits2f(xvg[1]);                \
      float gg = ((quad & 2) ? aB2[0] : aA2[0]) + bfbits2f(xvg[2]);                \
      float go = ((quad & 2) ? aB3[0] : aA3[0]) + bfbits2f(xvg[3]);                \
      float Af = exp2_(-1.4426950408889634f * gf);                                 \
      float Bi = exp2_(-1.4426950408889634f * gi);                                 \
      float Cg = exp2_(2.8853900817779268f * gg);                                  \
      float Fo = exp2_(-1.4426950408889634f * go);                                 \
      float oA = 1.f + Af, oB = 1.f + Bi, oC = 1.f + Cg;                           \
      float P = oB * oC;                                                           \
      float numer = cst * P + oA * (Cg - 1.f);                                     \
      cst = numer * __builtin_amdgcn_rcpf(oA * P);                                 \
      float hv = tanh_(cst) * __builtin_amdgcn_rcpf(1.f + Fo);                     \
      if (!(quad & 1)) *(((k) & 1) ? hw0 : hw1) = f2bf(hv);                        \
    }                                                                              \
    if (wv == 0) {                                                                 \
      f32x4 accE = __builtin_amdgcn_mfma_f32_16x16x32_bf16(af0, bfragE[0], ZACC, 0, 0, 0); \
      accE = __builtin_amdgcn_mfma_f32_16x16x32_bf16(af1, bfragE[1], accE, 0, 0, 0); \
      accE = __builtin_amdgcn_mfma_f32_16x16x32_bf16(af2, bfragE[2], accE, 0, 0, 0); \
      accE = __builtin_amdgcn_mfma_f32_16x16x32_bf16(af3, bfragE[3], accE, 0, 0, 0); \
      if (quad == 0 && n16 < NL_ && (m16 + KE) >= 1) {                             \
        int tprev = dir ? (S_ - (m16 + KE)) : (m16 + KE - 1);                      \
        emL[(tprev & 31) * 9 + n16] = accE[0];                                     \
      }                                                                            \
    }                                                                              \
    wg_bar();                                                                      \
  }

__global__ __launch_bounds__(256, 1)
void lstm_kernel(const int* __restrict__ seq, const ushort_t* __restrict__ embB,
                 const ushort_t* __restrict__ wihPack, const float* __restrict__ biasPack,
                 const float* __restrict__ w_hh_f, const float* __restrict__ w_hh_b,
                 const float* __restrict__ w_out,
                 float* __restrict__ em_f, float* __restrict__ em_b)
{
    __shared__ bf16x8 xwL[2 * 1024];           // 32 KB: [buf][t*512 + u*4 + nt] ushorts
    __shared__ bf16x8 hbuf[2][16];             // 512 B, double-buffered h (128 bf16/buf)
    __shared__ __align__(16) float emL[32 * NL_];  // 1152 B: [slot][label]

    const int tid  = threadIdx.x;
    const int wv   = tid >> 6;
    const int lane = tid & 63;
    const int n16  = tid & 15;
    const int quad = (tid & 63) >> 4;
    const int dir  = blockIdx.x >> 7;
    const int b    = blockIdx.x & 127;

    const int uu = wv * 32 + ((quad >> 1) << 4) + n16;   // unit owned by this lane

    // per-lane h-write pointers (buf0/buf1); writers are quads 0 and 2
    short* hw0 = ((short*)hbuf) + uu;
    short* hw1 = ((short*)hbuf) + 128 + uu;
    const short* xwS = (const short*)xwL;
    short* xwSW = (short*)xwL;

    const f32x4 ZACC = {0.f, 0.f, 0.f, 0.f};

    const float* whh = dir ? w_hh_b : w_hh_f;
    float* emdir = dir ? em_b : em_f;

    // W_hh fragments: bfrag[tile][gate][ks]; gate col = nt*128 + wv*32 + tl*16 + n16
    bf16x8 bfrag[2][4][4];
#pragma unroll
    for (int tl = 0; tl < 2; tl++) {
#pragma unroll
        for (int nt = 0; nt < 4; nt++) {
            int col = nt * 128 + wv * 32 + tl * 16 + n16;
#pragma unroll
            for (int ks = 0; ks < 4; ks++) {
                const float* p = whh + col * H_ + ks * 32 + quad * 8;
                bf16x8 fr;
#pragma unroll
                for (int j = 0; j < 8; j++) fr[j] = f2bf(p[j]);
                bfrag[tl][nt][ks] = fr;
            }
        }
    }
    bf16x8 bfragE[4];
#pragma unroll
    for (int ks = 0; ks < 4; ks++) {
        bf16x8 fr = {0, 0, 0, 0, 0, 0, 0, 0};
        if (n16 < NL_) {
            const float* p = w_out + n16 * 256 + dir * 128 + ks * 32 + quad * 8;
#pragma unroll
            for (int j = 0; j < 8; j++) fr[j] = f2bf(p[j]);
        }
        bfragE[ks] = fr;
    }

    // resident: fused biases + wihPack base for this (dir, wave)
    float4 bb0 = *(const float4*)(biasPack + ((dir * 4 + wv) * 2 + 0) * 64 + n16 * 4);
    float4 bb1 = *(const float4*)(biasPack + ((dir * 4 + wv) * 2 + 1) * 64 + n16 * 4);
    const ushort_t* wvbase = wihPack + (size_t)(dir * 4 + wv) * 16384 + (size_t)lane * 8;

    if (tid < 64) ((int*)hbuf)[tid] = 0;   // zero h buffer 0 (256 B)

    f32x4 x0, x1, x2, x3;
    bf16x8 afE0, afE1, afE2, afE3;

    // prolog: compute block 0's xw tile into buf 0 (serial mini-GEMM)
    {
        int t0s = dir ? (S_ - 16) : 0;
        int tok = seq[b * S_ + t0s + n16];
        const ushort_t* ep = embB + (size_t)tok * EMB_ + quad * 8;
        afE0 = *(const bf16x8*)(ep);
        afE1 = *(const bf16x8*)(ep + 32);
        afE2 = *(const bf16x8*)(ep + 64);
        afE3 = *(const bf16x8*)(ep + 96);
#pragma unroll
        for (int tl = 0; tl < 2; tl++) {
            float4 bv = tl ? bb1 : bb0;
            x0 = (f32x4){bv.x, bv.x, bv.x, bv.x};
            x1 = (f32x4){bv.y, bv.y, bv.y, bv.y};
            x2 = (f32x4){bv.z, bv.z, bv.z, bv.z};
            x3 = (f32x4){bv.w, bv.w, bv.w, bv.w};
#pragma unroll
            for (int ks = 0; ks < 4; ks++) {
                const ushort_t* wp = wvbase + (tl * 4 + ks) * 2048;
                bf16x8 f0 = *(const bf16x8*)(wp);
                bf16x8 f1 = *(const bf16x8*)(wp + 512);
                bf16x8 f2 = *(const bf16x8*)(wp + 1024);
                bf16x8 f3 = *(const bf16x8*)(wp + 1536);
                bf16x8 ae = (ks == 0) ? afE0 : (ks == 1) ? afE1 : (ks == 2) ? afE2 : afE3;
                x0 = __builtin_amdgcn_mfma_f32_16x16x32_bf16(ae, f0, x0, 0, 0, 0);
                x1 = __builtin_amdgcn_mfma_f32_16x16x32_bf16(ae, f1, x1, 0, 0, 0);
                x2 = __builtin_amdgcn_mfma_f32_16x16x32_bf16(ae, f2, x2, 0, 0, 0);
                x3 = __builtin_amdgcn_mfma_f32_16x16x32_bf16(ae, f3, x3, 0, 0, 0);
            }
            short* dstp = xwSW + (wv * 32 + tl * 16 + n16) * 4;
#pragma unroll
            for (int r = 0; r < 4; r++) {
                uint2 wq; wq.x = pack2(x0[r], x1[r]); wq.y = pack2(x2[r], x3[r]);
                *(uint2*)(dstp + (quad * 4 + r) * 512) = wq;
            }
        }
    }

    float cst = 0.f;
    wg_bar();

#pragma unroll 1
    for (int m = 0; m < 32; m++) {
        const int m16 = m << 4;
#pragma unroll 1
        for (int s4 = 0; s4 < 4; s4++) {
            const int s4x4 = s4 << 2;
            STEPK(0) STEPK(1) STEPK(2) STEPK(3)
        }
    }

    // final emission (h after step 512, in buf0), then tail flush
    if (wv == 0) {
        bf16x8 af0 = hbuf[0][0 * 4 + quad];
        bf16x8 af1 = hbuf[0][1 * 4 + quad];
        bf16x8 af2 = hbuf[0][2 * 4 + quad];
        bf16x8 af3 = hbuf[0][3 * 4 + quad];
        f32x4 accE = __builtin_amdgcn_mfma_f32_16x16x32_bf16(af0, bfragE[0], ZACC, 0, 0, 0);
        accE = __builtin_amdgcn_mfma_f32_16x16x32_bf16(af1, bfragE[1], accE, 0, 0, 0);
        accE = __builtin_amdgcn_mfma_f32_16x16x32_bf16(af2, bfragE[2], accE, 0, 0, 0);
        accE = __builtin_amdgcn_mfma_f32_16x16x32_bf16(af3, bfragE[3], accE, 0, 0, 0);
        if (quad == 0 && n16 < NL_) {
            int tprev = dir ? 0 : (S_ - 1);
            emL[(tprev & 31) * 9 + n16] = accE[0];
        }
    }
    wg_bar();
    if (wv == 3 && lane < 36) {
        int a0 = dir ? 0 : (S_ - 16);
        float4 fv = *(const float4*)(emL + (a0 & 31) * 9 + lane * 4);
        *(float4*)(emdir + (size_t)b * (S_ * NL_) + a0 * NL_ + lane * 4) = fv;
    }
}

// ---------------------------------------------------------------------------
// CRF with chunked parallel scan (unchanged from r6 — verified correct).
// ---------------------------------------------------------------------------
__global__ __launch_bounds__(640, 1)
void crf_kernel(const int* __restrict__ seq, const int* __restrict__ lab,
                const float* __restrict__ em_f, const float* __restrict__ em_b,
                const float* __restrict__ b_out,
                const float* __restrict__ start_t, const float* __restrict__ end_t,
                const float* __restrict__ trans, float* __restrict__ partial)
{
    __shared__ float emS[S_ * NL_];
    __shared__ float transS[NL_ * NL_];
    __shared__ float stS[NL_], enS[NL_];
    __shared__ unsigned char maskS[S_];
    __shared__ float MS[7 * 81];
    __shared__ float vS[NL_];
    __shared__ float redw[10];
    __shared__ int   redl[10];

    const int b = blockIdx.x, tid = threadIdx.x;
    const size_t base = (size_t)b * S_ * NL_;
    const float L2E = 1.4426950408889634f, LN2 = 0.6931471805599453f;

    for (int q = tid; q < S_ * NL_; q += 640)
        emS[q] = em_f[base + q] + em_b[base + q] + b_out[q % NL_];
    if (tid < NL_ * NL_) transS[tid] = trans[tid];
    if (tid < NL_) { stS[tid] = start_t[tid]; enS[tid] = end_t[tid]; }
    if (tid < S_) maskS[tid] = (seq[b * S_ + tid] != 0);
    __syncthreads();

    float np = 0.f; int myc = 0;
    if (tid < S_) {
        myc = maskS[tid];
        if (tid >= 1 && maskS[tid]) {
            int lp = lab[b * S_ + tid - 1], lc = lab[b * S_ + tid];
            np = transS[lp * NL_ + lc] + emS[tid * NL_ + lc];
        }
    }
#pragma unroll
    for (int off = 32; off; off >>= 1) {
        np  += __shfl_down(np, off, 64);
        myc += __shfl_down(myc, off, 64);
    }
    if ((tid & 63) == 0) { redw[tid >> 6] = np; redl[tid >> 6] = myc; }

    const int w = tid >> 6, l = tid & 63;
    const int lg = l / 9;
    const int g  = w * 7 + lg;
    const bool sact = (lg < 7) && (g < 64);
    const int jj = sact ? (l - lg * 9) : 0;
    const int gb = sact ? lg * 9 : 0;
    float Tc[NL_];
#pragma unroll
    for (int i = 0; i < NL_; i++) Tc[i] = transS[i * NL_ + jj];
    float sc; int tbeg, tend, cN = 0, iN = 0;
    if (sact && g == 0) {
        sc = stS[jj] + emS[jj];
        tbeg = 1; tend = 64;
    } else if (sact) {
        cN = 1 + (g - 1) / 9; iN = (g - 1) % 9;
        sc = (jj == iN) ? 0.f : -1e30f;
        tbeg = cN * 64; tend = tbeg + 64;
    } else {
        sc = -1e30f; tbeg = 448; tend = 512;
    }
    for (int t = tbeg; t < tend; t++) {
        float emv = emS[t * NL_ + jj];
        float a[NL_];
#pragma unroll
        for (int i = 0; i < NL_; i++) a[i] = __shfl(sc, gb + i, 64) + Tc[i];
        float m = max3_(max3_(a[0], a[1], a[2]), max3_(a[3], a[4], a[5]),
                        max3_(a[6], a[7], a[8]));
        float e[NL_];
#pragma unroll
        for (int i = 0; i < NL_; i++) e[i] = exp2_((a[i] - m) * L2E);
        float sum = ((e[0] + e[1]) + (e[2] + e[3])) + ((e[4] + e[5]) + (e[6] + e[7])) + e[8];
        float nxt = emv + m + LN2 * log2_(sum);
        sc = maskS[t] ? nxt : sc;
    }
    if (sact) {
        if (g == 0) vS[jj] = sc;
        else MS[(cN - 1) * 81 + iN * NL_ + jj] = sc;
    }
    __syncthreads();

    if (tid < 64) {
        const int j = (tid < NL_) ? tid : (NL_ - 1);
        float v = vS[j];
        for (int c = 1; c < 8; c++) {
            float a[NL_];
#pragma unroll
            for (int i = 0; i < NL_; i++)
                a[i] = __shfl(v, i, 64) + MS[(c - 1) * 81 + i * NL_ + j];
            float m = max3_(max3_(a[0], a[1], a[2]), max3_(a[3], a[4], a[5]),
                            max3_(a[6], a[7], a[8]));
            float e[NL_];
#pragma unroll
            for (int i = 0; i < NL_; i++) e[i] = exp2_((a[i] - m) * L2E);
            float sum = ((e[0] + e[1]) + (e[2] + e[3])) + ((e[4] + e[5]) + (e[6] + e[7])) + e[8];
            v = m + LN2 * log2_(sum);
        }
        v += enS[j];
        float mm = -1e30f, av[NL_];
#pragma unroll
        for (int i = 0; i < NL_; i++) { float vi = __shfl(v, i, 64); av[i] = vi; mm = fmaxf(mm, vi); }
        float ss = 0.f;
#pragma unroll
        for (int i = 0; i < NL_; i++) ss += exp2_((av[i] - mm) * L2E);
        if (tid == 0) {
            float num = 0.f; int len = 0;
#pragma unroll
            for (int ww = 0; ww < 10; ww++) { num += redw[ww]; len += redl[ww]; }
            int l0 = lab[b * S_];
            int ll = lab[b * S_ + len - 1];
            num += stS[l0] + emS[l0] + enS[ll];
            partial[b] = (mm + LN2 * log2_(ss)) - num;
        }
    }
}

__global__ __launch_bounds__(128)
void reduce_kernel(const float* __restrict__ partial, float* __restrict__ out)
{
    __shared__ float s[128];
    int tid = threadIdx.x;
    s[tid] = partial[tid];
    __syncthreads();
    for (int off = 64; off; off >>= 1) {
        if (tid < off) s[tid] += s[tid + off];
        __syncthreads();
    }
    if (tid == 0) out[0] = s[0];
}

extern "C" void kernel_launch(void* const* d_in, const int* in_sizes, int n_in,
                              void* d_out, int out_size, void* d_ws, size_t ws_size,
                              hipStream_t stream)
{
    const int* seq = (const int*)d_in[0];
    const int* lab = (const int*)d_in[1];
    const float* emb    = (const float*)d_in[2];
    const float* w_ih_f = (const float*)d_in[3];
    const float* w_hh_f = (const float*)d_in[4];
    const float* b_ih_f = (const float*)d_in[5];
    const float* b_hh_f = (const float*)d_in[6];
    const float* w_ih_b = (const float*)d_in[7];
    const float* w_hh_b = (const float*)d_in[8];
    const float* b_ih_b = (const float*)d_in[9];
    const float* b_hh_b = (const float*)d_in[10];
    const float* w_out  = (const float*)d_in[11];
    const float* b_out  = (const float*)d_in[12];
    const float* start_t = (const float*)d_in[13];
    const float* end_t   = (const float*)d_in[14];
    const float* trans   = (const float*)d_in[15];

    char* ws = (char*)d_ws;
    const size_t embB_bytes = (size_t)100000 * EMB_ * sizeof(ushort_t);   // 25.6 MB
    const size_t wih_bytes  = (size_t)16384 * 16;                         // 256 KB
    const size_t bias_bytes = 1024 * sizeof(float);                       // 4 KB
    const size_t em_bytes   = (size_t)B_ * S_ * NL_ * sizeof(float);      // 2.36 MB

    ushort_t* embB    = (ushort_t*)ws;
    ushort_t* wihPack = (ushort_t*)(ws + embB_bytes);
    float* biasPack   = (float*)(ws + embB_bytes + wih_bytes);
    float* em_f       = (float*)(ws + embB_bytes + wih_bytes + bias_bytes);
    float* em_b       = (float*)(ws + embB_bytes + wih_bytes + bias_bytes + em_bytes);
    float* partial    = (float*)(ws + embB_bytes + wih_bytes + bias_bytes + 2 * em_bytes);

    prep_kernel<<<dim3(NB_EMB + NB_WIH + 4), dim3(256), 0, stream>>>(emb,
        w_ih_f, w_ih_b, b_ih_f, b_hh_f, b_ih_b, b_hh_b, embB, wihPack, biasPack);
    lstm_kernel<<<dim3(256), dim3(256), 0, stream>>>(seq, embB, wihPack, biasPack,
        w_hh_f, w_hh_b, w_out, em_f, em_b);
    crf_kernel<<<dim3(B_), dim3(640), 0, stream>>>(seq, lab, em_f, em_b, b_out,
        start_t, end_t, trans, partial);
    reduce_kernel<<<dim3(1), dim3(128), 0, stream>>>(partial, (float*)d_out);
}